// Round 19
// baseline (110.814 us; speedup 1.0000x reference)
//
#include <hip/hip_runtime.h>
#include <hip/hip_bf16.h>
#include <math.h>

// VQ-VAE VectorQuantizer: B=32,T=2048,D=64,K=1024 -> N=65536 rows.
// Round 19: R18 (94.25us, absmax 0.0) + combine-derived top-2 rescore.
//  - combine sorts the 4 per-quarter winner keys (u64 = value<<32|j). If the
//    global 2nd-best comes from a DIFFERENT quarter (v2k < mm2, strict) and
//    the 3rd value min(v3k,mm2) > v1+EPSB, the exact argmin provably lies in
//    {j1,j2} (same gap argument as the certificate; EPSB=4e-5 > 2*delta).
//    -> vq_rescore2 (R15-proven exact 2-code chains) writes keyBest[row].
//    Else -> full exact scan (R13-frozen kernel) on the reduced scan list.
//  - minifinal covers ALL ambiguous rows uniformly via keyBest (R18 pattern).
//  - fused / prep / exact / cert rule / phase-2 certified output: R18-verbatim.
//    NO fused inner-loop changes (R15's mistake), NO device fences (R15/R16).

typedef __attribute__((ext_vector_type(8))) short bf16x8;
typedef __attribute__((ext_vector_type(4))) float f32x4;
typedef unsigned long long u64;

namespace {
constexpr int NROWS  = 65536;
constexpr int DDIM   = 64;
constexpr int KCODES = 1024;
constexpr float EPSB = 4e-5f;   // certificate band; bound ~1.7e-5 (2*delta)

// ws layout (bytes) — ~8.4 MB
constexpr size_t WS_LOSS  = 0;                             // double
constexpr size_t WS_CNT   = 64;                            // int[3]: scan, two, all
constexpr size_t WS_SE    = 256;                           // float[1024]
constexpr size_t WS_EHB   = 8192;                          // 128 KB
constexpr size_t WS_ELB   = WS_EHB  + (size_t)65536 * 2;   // 128 KB
constexpr size_t WS_LIST  = WS_ELB  + (size_t)65536 * 2;   // int[N] scan rows
constexpr size_t WS_ROWS2 = WS_LIST + (size_t)NROWS * 4;   // int[N] rescore2 rows
constexpr size_t WS_JJ2   = WS_ROWS2 + (size_t)NROWS * 4;  // int[N] packed j1,j2
constexpr size_t WS_LALL  = WS_JJ2  + (size_t)NROWS * 4;   // int[N] all ambiguous
constexpr size_t WS_KEY   = WS_LALL + (size_t)NROWS * 4;   // u64[N]
constexpr size_t WS_MV    = WS_KEY  + (size_t)NROWS * 8;   // float2[4][N]
constexpr size_t WS_KV    = WS_MV   + (size_t)4 * NROWS * 8; // u64[4][N]
}

__device__ inline short f2bf(float v) {
  __hip_bfloat16 h = __float2bfloat16(v);
  return *reinterpret_cast<short*>(&h);
}
__device__ inline float bf2f(short s) {
  __hip_bfloat16 h;
  *reinterpret_cast<short*>(&h) = s;
  return __bfloat162float(h);
}
__device__ inline f32x4 mfma16(bf16x8 a, bf16x8 b, f32x4 c) {
  return __builtin_amdgcn_mfma_f32_16x16x32_bf16(a, b, c, 0, 0, 0);
}
__device__ inline unsigned int fflip(unsigned int b) {
  return b ^ ((unsigned int)((int)b >> 31) | 0x80000000u);
}
__device__ inline float kval(u64 k) {   // inverse of fflip on key's high word
  unsigned u = (unsigned)(k >> 32);
  u ^= ((int)u < 0) ? 0x80000000u : 0xFFFFFFFFu;
  return __uint_as_float(u);
}

// ---------------- prep: init keyBest/loss/cnts, se (numpy pairwise), frag pack
__global__ __launch_bounds__(256) void vq_prep(const float* __restrict__ emb,
                                               float* __restrict__ se,
                                               short* __restrict__ ehB,
                                               short* __restrict__ elB,
                                               u64* __restrict__ keyBest,
                                               double* __restrict__ loss_accum,
                                               int* __restrict__ cnts) {
  #pragma clang fp contract(off)
  const int gid = blockIdx.x * 256 + (int)threadIdx.x;   // grid = 65536
  if (gid == 0) { *loss_accum = 0.0; cnts[0] = 0; cnts[1] = 0; cnts[2] = 0; }
  keyBest[gid] = ~0ull;

  if (gid < KCODES) {   // se[j]: proven pairwise pattern
    const float* e = emb + (size_t)gid * DDIM;
    float r[8];
    #pragma unroll
    for (int j = 0; j < 8; ++j) r[j] = e[j] * e[j];
    #pragma unroll
    for (int i = 8; i < DDIM; i += 8) {
      #pragma unroll
      for (int j = 0; j < 8; ++j) r[j] += e[i + j] * e[i + j];
    }
    se[gid] = ((r[0] + r[1]) + (r[2] + r[3])) + ((r[4] + r[5]) + (r[6] + r[7]));
  }

  // pack frag (t,dc): lane l holds e[t*16+(l&15)][dc*32+(l>>4)*8 + i]  (R5-R18)
  if (gid < 8192) {
    const int t  = gid >> 7;
    const int dc = (gid >> 6) & 1;
    const int l  = gid & 63;
    const int code = t * 16 + (l & 15);
    const int d0   = dc * 32 + (l >> 4) * 8;
    const float* ep = emb + (size_t)code * DDIM + d0;
    const size_t ob = ((size_t)(t * 2 + dc) * 64 + l) * 8;
    #pragma unroll
    for (int i = 0; i < 8; ++i) {
      const float v = ep[i];
      const short h = f2bf(v);
      ehB[ob + i] = h;
      elB[ob + i] = f2bf(v - bf2f(h));
    }
  }
}

// ---------------- fused sweep: block = 128 rows x 256 codes (R13/R18-verbatim)
__global__ __launch_bounds__(256, 2) void vq_fused(const float* __restrict__ x,
                                                   const short* __restrict__ ehB,
                                                   const short* __restrict__ elB,
                                                   const float* __restrict__ se,
                                                   float2* __restrict__ mv,
                                                   u64* __restrict__ kv) {
  #pragma clang fp contract(off)
  __shared__ float sel[256];                     // this quarter's se values
  const int tid  = (int)threadIdx.x;
  const int l    = tid & 63;
  const int wid  = tid >> 6;
  const int quar = (int)blockIdx.x & 3;          // K-quarter: tiles [q*16, q*16+16)
  const int rblk = (int)blockIdx.x >> 2;
  const int t0   = quar * 16;
  sel[tid] = se[t0 * 16 + tid];
  __syncthreads();

  // A-fragments for 2 row-tiles (32 rows/wave)
  const int wrb = rblk * 128 + wid * 32;
  bf16x8 xh[2][2], xl[2][2];
  #pragma unroll
  for (int rt = 0; rt < 2; ++rt) {
    const float* xp = x + (size_t)(wrb + rt * 16 + (l & 15)) * DDIM + (l >> 4) * 8;
    #pragma unroll
    for (int dc = 0; dc < 2; ++dc) {
      const float4 v0 = *reinterpret_cast<const float4*>(xp + dc * 32);
      const float4 v1 = *reinterpret_cast<const float4*>(xp + dc * 32 + 4);
      const float vv[8] = {v0.x, v0.y, v0.z, v0.w, v1.x, v1.y, v1.z, v1.w};
      #pragma unroll
      for (int i = 0; i < 8; ++i) {
        const short h = f2bf(vv[i]);
        xh[rt][dc][i] = h;
        xl[rt][dc][i] = f2bf(vv[i] - bf2f(h));
      }
    }
  }

  float m1v[2][4], m2v[2][4];
  int   m1t[2][4];
  #pragma unroll
  for (int rt = 0; rt < 2; ++rt)
    #pragma unroll
    for (int r = 0; r < 4; ++r) { m1v[rt][r] = INFINITY; m2v[rt][r] = INFINITY; m1t[rt][r] = 0; }

  const size_t lb = (size_t)l * 8;
#define FRAGLD(buf, tt, half2) \
  (*reinterpret_cast<const bf16x8*>((buf) + (size_t)(tt) * 1024 + (half2) * 512 + lb))

  // 2-deep pipeline: tiles t (cur) / t+1 (nxt) in flight while computing.
  bf16x8 c0 = FRAGLD(ehB, t0, 0), c1 = FRAGLD(ehB, t0, 1),
         c2 = FRAGLD(elB, t0, 0), c3 = FRAGLD(elB, t0, 1);
  bf16x8 n0 = FRAGLD(ehB, t0 + 1, 0), n1 = FRAGLD(ehB, t0 + 1, 1),
         n2 = FRAGLD(elB, t0 + 1, 0), n3 = FRAGLD(elB, t0 + 1, 1);

  const f32x4 kz = {0.f, 0.f, 0.f, 0.f};
  #pragma unroll 4
  for (int tt = 0; tt < 16; ++tt) {
    const int t = t0 + tt;
    const int tf = (tt + 2 < 16) ? t + 2 : t0 + 15;   // clamp (dup loads harmless)
    bf16x8 f0 = FRAGLD(ehB, tf, 0), f1 = FRAGLD(ehB, tf, 1),
           f2 = FRAGLD(elB, tf, 0), f3 = FRAGLD(elB, tf, 1);

    f32x4 a0, a1;   // interleave the two row-tiles: dep distance 2 on MFMA pipe
    a0 = mfma16(xh[0][0], c0, kz);  a1 = mfma16(xh[1][0], c0, kz);
    a0 = mfma16(xh[0][1], c1, a0);  a1 = mfma16(xh[1][1], c1, a1);
    a0 = mfma16(xh[0][0], c2, a0);  a1 = mfma16(xh[1][0], c2, a1);
    a0 = mfma16(xh[0][1], c3, a0);  a1 = mfma16(xh[1][1], c3, a1);
    a0 = mfma16(xl[0][0], c0, a0);  a1 = mfma16(xl[1][0], c0, a1);
    a0 = mfma16(xl[0][1], c1, a0);  a1 = mfma16(xl[1][1], c1, a1);

    const float sev = sel[tt * 16 + (l & 15)];
    #pragma unroll
    for (int r = 0; r < 4; ++r) {
      {
        const float d = __builtin_fmaf(-2.0f, a0[r], sev);  // d' = se - 2*dot
        const bool c = d < m1v[0][r];
        m2v[0][r] = fminf(m2v[0][r], fmaxf(m1v[0][r], d));
        m1t[0][r] = c ? t : m1t[0][r];
        m1v[0][r] = fminf(m1v[0][r], d);
      }
      {
        const float d = __builtin_fmaf(-2.0f, a1[r], sev);
        const bool c = d < m1v[1][r];
        m2v[1][r] = fminf(m2v[1][r], fmaxf(m1v[1][r], d));
        m1t[1][r] = c ? t : m1t[1][r];
        m1v[1][r] = fminf(m1v[1][r], d);
      }
    }
    c0 = n0; c1 = n1; c2 = n2; c3 = n3;
    n0 = f0; n1 = f1; n2 = f2; n3 = f3;
  }
#undef FRAGLD

  // 16-lane merge (R6-R18-proven); emit per-quarter partials
  const int colbase = l & 15;
  #pragma unroll
  for (int rt = 0; rt < 2; ++rt) {
    #pragma unroll
    for (int r = 0; r < 4; ++r) {
      float m1 = m1v[rt][r], m2 = m2v[rt][r];
      u64 key = ((u64)fflip(__float_as_uint(m1)) << 32)
                | (unsigned)(m1t[rt][r] * 16 + colbase);
      #pragma unroll
      for (int off = 1; off < 16; off <<= 1) {
        const u64 ok = __shfl_xor(key, off, 16);
        const float om1 = __shfl_xor(m1, off, 16);
        const float om2 = __shfl_xor(m2, off, 16);
        m2 = fminf(fminf(m2, om2), fmaxf(m1, om1));
        m1 = fminf(m1, om1);
        key = (ok < key) ? ok : key;
      }
      if (colbase == 0) {
        const int row = wrb + rt * 16 + (l >> 4) * 4 + r;
        mv[(size_t)quar * NROWS + row] = make_float2(m1, m2);
        kv[(size_t)quar * NROWS + row] = key;
      }
    }
  }
}

// ---------------- combine + certified-row finalize + 3-way routing
__global__ __launch_bounds__(256) void vq_combine_out(const float2* __restrict__ mv,
                                                      const u64* __restrict__ kv,
                                                      const float* __restrict__ x,
                                                      const float* __restrict__ emb,
                                                      int* __restrict__ listScan,
                                                      int* __restrict__ rows2,
                                                      int* __restrict__ jj2,
                                                      int* __restrict__ listAll,
                                                      int* __restrict__ cnts,
                                                      float* __restrict__ out,
                                                      double* __restrict__ loss_accum) {
  #pragma clang fp contract(off)
  __shared__ int   sbidx[256];
  __shared__ float wsum[4];
  const int tid = (int)threadIdx.x;
  const int gid = blockIdx.x * 256 + tid;
  const int l   = tid & 63;

  // ---- phase 1: tournament (via sorted keys) + certificate ladder + routing
  {
    const float2 A = mv[gid];
    const float2 B = mv[(size_t)NROWS + gid];
    const float2 C = mv[(size_t)2 * NROWS + gid];
    const float2 D = mv[(size_t)3 * NROWS + gid];
    u64 e0 = kv[gid];
    u64 e1 = kv[(size_t)NROWS + gid];
    u64 e2 = kv[(size_t)2 * NROWS + gid];
    u64 e3 = kv[(size_t)3 * NROWS + gid];
    // sort 4 keys (u64 order == (value asc, j asc)); 5-comparator network
    { u64 t; if (e1 < e0) { t = e0; e0 = e1; e1 = t; } }
    { u64 t; if (e3 < e2) { t = e2; e2 = e3; e3 = t; } }
    { u64 t; if (e2 < e0) { t = e0; e0 = e2; e2 = t; } }
    { u64 t; if (e3 < e1) { t = e1; e1 = e3; e3 = t; } }
    { u64 t; if (e2 < e1) { t = e1; e1 = e2; e2 = t; } }
    const float v1  = kval(e0);
    const float v2k = kval(e1);
    const float v3k = kval(e2);
    const float mm2 = fminf(fminf(A.y, B.y), fminf(C.y, D.y));

    const float m2g = fminf(v2k, mm2);                 // == R13 tournament m2g
    const bool cert = m2g > v1 + EPSB;                 // unique winner
    const bool twoQ = !cert && (v2k < mm2) &&          // 2nd key known (strict)
                      (fminf(v3k, mm2) > v1 + EPSB);   // 3rd outside band
    sbidx[tid] = cert ? (int)(e0 & 0xffffffffull) : -1;

    {  // compaction: all-ambiguous list (for minifinal)
      const u64 mask = __ballot(!cert);
      int base = 0;
      if (l == 0 && mask) base = atomicAdd(&cnts[2], (int)__popcll(mask));
      base = __shfl(base, 0, 64);
      if (!cert) {
        const int off = (int)__popcll(mask & ((1ull << l) - 1ull));
        listAll[base + off] = gid;
      }
    }
    {  // compaction: rescore2 list
      const u64 mask = __ballot(twoQ);
      int base = 0;
      if (l == 0 && mask) base = atomicAdd(&cnts[1], (int)__popcll(mask));
      base = __shfl(base, 0, 64);
      if (twoQ) {
        const int off = (int)__popcll(mask & ((1ull << l) - 1ull));
        rows2[base + off] = gid;
        jj2[base + off] = ((int)(e0 & 0xffffull) << 16) | (int)(e1 & 0xffffull);
      }
    }
    {  // compaction: full-scan list
      const bool scan = !cert && !twoQ;
      const u64 mask = __ballot(scan);
      int base = 0;
      if (l == 0 && mask) base = atomicAdd(&cnts[0], (int)__popcll(mask));
      base = __shfl(base, 0, 64);
      if (scan) {
        const int off = (int)__popcll(mask & ((1ull << l) - 1ull));
        listScan[base + off] = gid;
      }
    }
  }
  __syncthreads();

  // ---- phase 2: finalize certified rows (R18-proven arithmetic/pattern)
  const int wid = tid >> 6;
  const int sub = l >> 4;    // row within the wave's quad
  const int q16 = l & 15;    // float4 slot within the row
  float lacc = 0.f;

  for (int it = 0; it < 16; ++it) {   // block covers its 256 rows
    const int rloc = it * 16 + wid * 4 + sub;
    const int bi = sbidx[rloc];       // uniform within the 16-lane group
    if (bi < 0) continue;             // ambiguous -> minifinal handles
    const int row = blockIdx.x * 256 + rloc;
    const float4 xv = reinterpret_cast<const float4*>(x)[(size_t)row * 16 + q16];
    const float4 ev = reinterpret_cast<const float4*>(emb)[(size_t)bi * 16 + q16];
    const float da = ev.x - xv.x;
    const float db = ev.y - xv.y;
    const float dc = ev.z - xv.z;
    const float dd = ev.w - xv.w;
    float4 o;
    o.x = xv.x + da; o.y = xv.y + db; o.z = xv.z + dc; o.w = xv.w + dd;
    reinterpret_cast<float4*>(out)[(size_t)row * 16 + q16] = o;
    lacc += da * da + db * db + dc * dc + dd * dd;   // order-insensitive
    if (q16 == 0) out[(size_t)NROWS * DDIM + row] = (float)bi;
  }
  #pragma unroll
  for (int off = 32; off > 0; off >>= 1) lacc += __shfl_down(lacc, off, 64);
  if (l == 0) wsum[wid] = lacc;
  __syncthreads();
  if (tid == 0)
    atomicAdd(loss_accum, (double)(wsum[0] + wsum[1] + wsum[2] + wsum[3]));
}

// ---------------- rescore2 (R15-proven chains): exact keys for {j1,j2}
__global__ __launch_bounds__(256) void vq_rescore2(const float* __restrict__ x,
                                                   const float* __restrict__ emb,
                                                   const float* __restrict__ se,
                                                   const int* __restrict__ rows2,
                                                   const int* __restrict__ jj2,
                                                   const int* __restrict__ cnts,
                                                   u64* __restrict__ keyBest) {
  #pragma clang fp contract(off)
  const int n2 = cnts[1];
  for (int idx = blockIdx.x * 256 + (int)threadIdx.x; idx < n2;
       idx += (int)gridDim.x * 256) {
    const int row = rows2[idx];
    const int jj  = jj2[idx];
    const int j1  = jj >> 16;
    const int j2  = jj & 0xffff;
    const float4* xr4 = reinterpret_cast<const float4*>(x + (size_t)row * DDIM);
    const float4* e14 = reinterpret_cast<const float4*>(emb + (size_t)j1 * DDIM);
    const float4* e24 = reinterpret_cast<const float4*>(emb + (size_t)j2 * DDIM);

    // sx: numpy pairwise 8-accumulator (proven float4-streaming form)
    float rr[8];
    {
      const float4 a = xr4[0], b = xr4[1];
      rr[0] = a.x * a.x; rr[1] = a.y * a.y; rr[2] = a.z * a.z; rr[3] = a.w * a.w;
      rr[4] = b.x * b.x; rr[5] = b.y * b.y; rr[6] = b.z * b.z; rr[7] = b.w * b.w;
    }
    #pragma unroll
    for (int i = 2; i < 16; i += 2) {
      const float4 a = xr4[i], b = xr4[i + 1];
      rr[0] += a.x * a.x; rr[1] += a.y * a.y; rr[2] += a.z * a.z; rr[3] += a.w * a.w;
      rr[4] += b.x * b.x; rr[5] += b.y * b.y; rr[6] += b.z * b.z; rr[7] += b.w * b.w;
    }
    const float sx = ((rr[0] + rr[1]) + (rr[2] + rr[3])) + ((rr[4] + rr[5]) + (rr[6] + rr[7]));

    // two sequential d=0..63 fmaf chains (bit-exact R1 order)
    float a1 = 0.f, a2 = 0.f;
    #pragma unroll
    for (int q = 0; q < 16; ++q) {
      const float4 xv = xr4[q];
      const float4 v1 = e14[q];
      const float4 v2 = e24[q];
      a1 = __builtin_fmaf(xv.x, v1.x, a1); a1 = __builtin_fmaf(xv.y, v1.y, a1);
      a1 = __builtin_fmaf(xv.z, v1.z, a1); a1 = __builtin_fmaf(xv.w, v1.w, a1);
      a2 = __builtin_fmaf(xv.x, v2.x, a2); a2 = __builtin_fmaf(xv.y, v2.y, a2);
      a2 = __builtin_fmaf(xv.z, v2.z, a2); a2 = __builtin_fmaf(xv.w, v2.w, a2);
    }
    const float T1 = sx + se[j1];                      // fl(sx + se_j)
    const float T2 = sx + se[j2];
    const float D1 = __builtin_fmaf(-2.0f, a1, T1);    // fl(T - 2*acc)
    const float D2 = __builtin_fmaf(-2.0f, a2, T2);
    const u64 k1 = ((u64)fflip(__float_as_uint(D1)) << 32) | (unsigned)j1;
    const u64 k2 = ((u64)fflip(__float_as_uint(D2)) << 32) | (unsigned)j2;
    keyBest[row] = (k1 < k2) ? k1 : k2;   // sole writer; (dist asc, j asc)
  }
}

// ---------------- exact scan (R13-frozen): 1-wave blocks, 32-code LDS parts
__global__ __launch_bounds__(64) void vq_exact(const float* __restrict__ x,
                                               const float* __restrict__ emb,
                                               const float* __restrict__ se,
                                               const int* __restrict__ list,
                                               const int* __restrict__ cnts,
                                               u64* __restrict__ keyBest) {
  #pragma clang fp contract(off)
  __shared__ __align__(16) float eL[32 * DDIM];   // 8 KB: one part's 32 codes
  const int n = cnts[0];
  if (n == 0) return;
  const int nrb = (n + 63) >> 6;
  const int ntasks = nrb * 32;
  const int l = (int)threadIdx.x;                 // 0..63

  for (int t = (int)blockIdx.x; t < ntasks; t += (int)gridDim.x) {
    const int part = t & 31;
    const int rb   = t >> 5;
    const int j0   = part * 32;

    {  // stage this part's 32 e-rows (coalesced float4)
      const float4* src = reinterpret_cast<const float4*>(emb + (size_t)j0 * DDIM);
      float4* dst = reinterpret_cast<float4*>(eL);
      #pragma unroll
      for (int i = 0; i < 8; ++i) dst[i * 64 + l] = src[i * 64 + l];
    }
    __syncthreads();

    const int idx = rb * 64 + l;
    const bool act = idx < n;
    const int row = act ? list[idx] : 0;
    const float4* xr4 = reinterpret_cast<const float4*>(x + (size_t)row * DDIM);

    float xv[DDIM];   // x row -> regs once
    #pragma unroll
    for (int q = 0; q < 16; ++q) {
      const float4 v = xr4[q];
      xv[q * 4 + 0] = v.x; xv[q * 4 + 1] = v.y;
      xv[q * 4 + 2] = v.z; xv[q * 4 + 3] = v.w;
    }

    // sx: numpy pairwise 8-accumulator (R1-proven order)
    float rr[8];
    #pragma unroll
    for (int j = 0; j < 8; ++j) rr[j] = xv[j] * xv[j];
    #pragma unroll
    for (int i = 8; i < DDIM; i += 8) {
      #pragma unroll
      for (int j = 0; j < 8; ++j) rr[j] += xv[i + j] * xv[i + j];
    }
    const float sx = ((rr[0] + rr[1]) + (rr[2] + rr[3])) + ((rr[4] + rr[5]) + (rr[6] + rr[7]));

    u64 best = ~0ull;
    #pragma unroll 1
    for (int g = 0; g < 8; ++g) {   // 8 groups of 4 codes; 4 chains
      const int jb = g * 4;
      const float4* e0 = reinterpret_cast<const float4*>(eL + (jb + 0) * DDIM);
      const float4* e1 = reinterpret_cast<const float4*>(eL + (jb + 1) * DDIM);
      const float4* e2 = reinterpret_cast<const float4*>(eL + (jb + 2) * DDIM);
      const float4* e3 = reinterpret_cast<const float4*>(eL + (jb + 3) * DDIM);
      float a0 = 0.f, a1 = 0.f, a2 = 0.f, a3 = 0.f;
      #pragma unroll
      for (int q = 0; q < 16; ++q) {   // per code: sequential d=0..63 (R1 chain)
        const float4 v0 = e0[q], v1 = e1[q], v2 = e2[q], v3 = e3[q];
        const float xa = xv[q * 4 + 0], xb = xv[q * 4 + 1];
        const float xc = xv[q * 4 + 2], xd = xv[q * 4 + 3];
        a0 = __builtin_fmaf(xa, v0.x, a0); a0 = __builtin_fmaf(xb, v0.y, a0);
        a0 = __builtin_fmaf(xc, v0.z, a0); a0 = __builtin_fmaf(xd, v0.w, a0);
        a1 = __builtin_fmaf(xa, v1.x, a1); a1 = __builtin_fmaf(xb, v1.y, a1);
        a1 = __builtin_fmaf(xc, v1.z, a1); a1 = __builtin_fmaf(xd, v1.w, a1);
        a2 = __builtin_fmaf(xa, v2.x, a2); a2 = __builtin_fmaf(xb, v2.y, a2);
        a2 = __builtin_fmaf(xc, v2.z, a2); a2 = __builtin_fmaf(xd, v2.w, a2);
        a3 = __builtin_fmaf(xa, v3.x, a3); a3 = __builtin_fmaf(xb, v3.y, a3);
        a3 = __builtin_fmaf(xc, v3.z, a3); a3 = __builtin_fmaf(xd, v3.w, a3);
      }
      const int j = j0 + jb;
      const float T0 = sx + se[j + 0];                    // fl(sx + se_j)
      const float T1 = sx + se[j + 1];
      const float T2 = sx + se[j + 2];
      const float T3 = sx + se[j + 3];
      const float di0 = __builtin_fmaf(-2.0f, a0, T0);    // fl(T - 2*acc)
      const float di1 = __builtin_fmaf(-2.0f, a1, T1);
      const float di2 = __builtin_fmaf(-2.0f, a2, T2);
      const float di3 = __builtin_fmaf(-2.0f, a3, T3);
      u64 k;
      k = ((u64)fflip(__float_as_uint(di0)) << 32) | (unsigned)(j + 0);
      best = (k < best) ? k : best;
      k = ((u64)fflip(__float_as_uint(di1)) << 32) | (unsigned)(j + 1);
      best = (k < best) ? k : best;
      k = ((u64)fflip(__float_as_uint(di2)) << 32) | (unsigned)(j + 2);
      best = (k < best) ? k : best;
      k = ((u64)fflip(__float_as_uint(di3)) << 32) | (unsigned)(j + 3);
      best = (k < best) ? k : best;
    }
    if (act) atomicMin(&keyBest[row], best);   // (dist asc, j asc) == first-min
    __syncthreads();                           // eL reuse barrier (1-wave: cheap)
  }
}

// ---------------- minifinal: all ambiguous rows via keyBest (R18 pattern)
__global__ __launch_bounds__(256) void vq_minifinal(const float* __restrict__ x,
                                                    const float* __restrict__ emb,
                                                    const int* __restrict__ listAll,
                                                    const int* __restrict__ cnts,
                                                    const u64* __restrict__ keyBest,
                                                    float* __restrict__ out,
                                                    double* __restrict__ loss_accum) {
  #pragma clang fp contract(off)
  const int n = cnts[2];
  const int l   = (int)threadIdx.x & 63;
  const int sub = l >> 4;
  const int q16 = l & 15;
  const int w   = blockIdx.x * 4 + ((int)threadIdx.x >> 6);
  const int nW  = (int)gridDim.x * 4;
  float lacc = 0.f;

  for (int base = w * 4; base < n; base += nW * 4) {
    const int i = base + sub;     // uniform within 16-lane group
    if (i >= n) continue;
    const int row = listAll[i];
    const int bi = (int)(keyBest[row] & 0xffffffffull);
    const float4 xv = reinterpret_cast<const float4*>(x)[(size_t)row * 16 + q16];
    const float4 ev = reinterpret_cast<const float4*>(emb)[(size_t)bi * 16 + q16];
    const float da = ev.x - xv.x;
    const float db = ev.y - xv.y;
    const float dc = ev.z - xv.z;
    const float dd = ev.w - xv.w;
    float4 o;
    o.x = xv.x + da; o.y = xv.y + db; o.z = xv.z + dc; o.w = xv.w + dd;
    reinterpret_cast<float4*>(out)[(size_t)row * 16 + q16] = o;
    lacc += da * da + db * db + dc * dc + dd * dd;
    if (q16 == 0) out[(size_t)NROWS * DDIM + row] = (float)bi;
  }
  #pragma unroll
  for (int off = 32; off > 0; off >>= 1) lacc += __shfl_down(lacc, off, 64);
  if (l == 0 && lacc != 0.f) atomicAdd(loss_accum, (double)lacc);
}

// ---------------- scalars
__global__ void vq_scalars(const double* __restrict__ loss_accum,
                           float* __restrict__ out) {
  if (threadIdx.x == 0 && blockIdx.x == 0) {
    const double mm = *loss_accum / (double)((size_t)NROWS * DDIM);
    const float el = (float)mm;
    float* tail = out + (size_t)NROWS * DDIM + NROWS;
    tail[0] = 0.25f * el;
    tail[1] = el;
    tail[2] = 0.0f;
  }
}

// ============================================================================
extern "C" void kernel_launch(void* const* d_in, const int* in_sizes, int n_in,
                              void* d_out, int out_size, void* d_ws, size_t ws_size,
                              hipStream_t stream) {
  const float* x   = (const float*)d_in[0];  // [N, 64]
  const float* emb = (const float*)d_in[1];  // [K, 64]
  float* out = (float*)d_out;
  char* ws = (char*)d_ws;

  double* loss_accum = (double*)(ws + WS_LOSS);
  int*    cnts       = (int*)(ws + WS_CNT);   // [0]=scan, [1]=rescore2, [2]=all
  float*  se         = (float*)(ws + WS_SE);
  short*  ehB        = (short*)(ws + WS_EHB);
  short*  elB        = (short*)(ws + WS_ELB);
  int*    listScan   = (int*)(ws + WS_LIST);
  int*    rows2      = (int*)(ws + WS_ROWS2);
  int*    jj2        = (int*)(ws + WS_JJ2);
  int*    listAll    = (int*)(ws + WS_LALL);
  u64*    keyBest    = (u64*)(ws + WS_KEY);
  float2* mv         = (float2*)(ws + WS_MV);
  u64*    kv         = (u64*)(ws + WS_KV);

  vq_prep<<<NROWS / 256, 256, 0, stream>>>(emb, se, ehB, elB, keyBest,
                                           loss_accum, cnts);
  vq_fused<<<(NROWS / 128) * 4, 256, 0, stream>>>(x, ehB, elB, se, mv, kv);
  vq_combine_out<<<NROWS / 256, 256, 0, stream>>>(mv, kv, x, emb, listScan,
                                                  rows2, jj2, listAll, cnts,
                                                  out, loss_accum);
  vq_rescore2<<<256, 256, 0, stream>>>(x, emb, se, rows2, jj2, cnts, keyBest);
  vq_exact<<<2048, 64, 0, stream>>>(x, emb, se, listScan, cnts, keyBest);
  vq_minifinal<<<256, 256, 0, stream>>>(x, emb, listAll, cnts, keyBest, out,
                                        loss_accum);
  vq_scalars<<<1, 64, 0, stream>>>(loss_accum, out);
}

// Round 20
// 94.010 us; speedup vs baseline: 1.1787x; 1.1787x over previous
//
#include <hip/hip_runtime.h>
#include <hip/hip_bf16.h>
#include <math.h>

// VQ-VAE VectorQuantizer: B=32,T=2048,D=64,K=1024 -> N=65536 rows.
// Round 20: byte-for-byte restore of Round 18 (94.25us, absmax 0.0) -- the
// session's best measured configuration. R19's 3-way routing regressed +16us
// (exact scan is granularity-bound, not n-bound; extra launch + compaction
// overhead). Final structure:
//   prep (se + bf16 hi/lo fragment pack + inits)
//   -> fused MFMA sweep (128 rows x 256 codes, K-split x4, min1/min2/tile)
//   -> combine_out (4-way tournament, EPSB certificate, certified-row
//      finalize fused in-kernel, ambiguous compaction)
//   -> exact scan (R1-bit-exact chains, 1-wave blocks, 32-code LDS parts)
//   -> minifinal (ambiguous rows via keyBest) -> scalars.
// Exactness: certified rows proven by gap argument (EPSB=4e-5 >= ~4x error
// bound); ambiguous rows rescored with numpy-bit-identical fp32 chains;
// u64 (fflip(dist)<<32|j) ordering == numpy first-min. absmax 0.0 throughout.

typedef __attribute__((ext_vector_type(8))) short bf16x8;
typedef __attribute__((ext_vector_type(4))) float f32x4;

namespace {
constexpr int NROWS  = 65536;
constexpr int DDIM   = 64;
constexpr int KCODES = 1024;
constexpr float EPSB = 4e-5f;   // certificate band; bound ~1.05e-5

// ws layout (bytes) — ~7.6 MB
constexpr size_t WS_LOSS = 0;                            // double
constexpr size_t WS_CNT  = 64;                           // int
constexpr size_t WS_SE   = 256;                          // float[1024]
constexpr size_t WS_EHB  = 8192;                         // bf16 frags 128 KB
constexpr size_t WS_ELB  = WS_EHB + (size_t)65536 * 2;   // 128 KB
constexpr size_t WS_BIDX = WS_ELB + (size_t)65536 * 2;   // int[N] (unused, kept)
constexpr size_t WS_LIST = WS_BIDX + (size_t)NROWS * 4;  // int[N]
constexpr size_t WS_KEY  = WS_LIST + (size_t)NROWS * 4;  // u64[N]
constexpr size_t WS_MV   = WS_KEY + (size_t)NROWS * 8;   // float2[4][N]
constexpr size_t WS_KV   = WS_MV + (size_t)4 * NROWS * 8; // u64[4][N]
}

__device__ inline short f2bf(float v) {
  __hip_bfloat16 h = __float2bfloat16(v);
  return *reinterpret_cast<short*>(&h);
}
__device__ inline float bf2f(short s) {
  __hip_bfloat16 h;
  *reinterpret_cast<short*>(&h) = s;
  return __bfloat162float(h);
}
__device__ inline f32x4 mfma16(bf16x8 a, bf16x8 b, f32x4 c) {
  return __builtin_amdgcn_mfma_f32_16x16x32_bf16(a, b, c, 0, 0, 0);
}
__device__ inline unsigned int fflip(unsigned int b) {
  return b ^ ((unsigned int)((int)b >> 31) | 0x80000000u);
}

// ---------------- prep: init keyBest/loss/cnt, se (numpy pairwise), frag pack
__global__ __launch_bounds__(256) void vq_prep(const float* __restrict__ emb,
                                               float* __restrict__ se,
                                               short* __restrict__ ehB,
                                               short* __restrict__ elB,
                                               unsigned long long* __restrict__ keyBest,
                                               double* __restrict__ loss_accum,
                                               int* __restrict__ cnt) {
  #pragma clang fp contract(off)
  const int gid = blockIdx.x * 256 + (int)threadIdx.x;   // grid = 65536
  if (gid == 0) { *loss_accum = 0.0; *cnt = 0; }
  keyBest[gid] = ~0ull;

  if (gid < KCODES) {   // se[j]: proven pairwise pattern
    const float* e = emb + (size_t)gid * DDIM;
    float r[8];
    #pragma unroll
    for (int j = 0; j < 8; ++j) r[j] = e[j] * e[j];
    #pragma unroll
    for (int i = 8; i < DDIM; i += 8) {
      #pragma unroll
      for (int j = 0; j < 8; ++j) r[j] += e[i + j] * e[i + j];
    }
    se[gid] = ((r[0] + r[1]) + (r[2] + r[3])) + ((r[4] + r[5]) + (r[6] + r[7]));
  }

  // pack frag (t,dc): lane l holds e[t*16+(l&15)][dc*32+(l>>4)*8 + i]  (R5-R18)
  if (gid < 8192) {
    const int t  = gid >> 7;
    const int dc = (gid >> 6) & 1;
    const int l  = gid & 63;
    const int code = t * 16 + (l & 15);
    const int d0   = dc * 32 + (l >> 4) * 8;
    const float* ep = emb + (size_t)code * DDIM + d0;
    const size_t ob = ((size_t)(t * 2 + dc) * 64 + l) * 8;
    #pragma unroll
    for (int i = 0; i < 8; ++i) {
      const float v = ep[i];
      const short h = f2bf(v);
      ehB[ob + i] = h;
      elB[ob + i] = f2bf(v - bf2f(h));
    }
  }
}

// ---------------- fused sweep: block = 128 rows x 256 codes (K-split x4)
__global__ __launch_bounds__(256, 2) void vq_fused(const float* __restrict__ x,
                                                   const short* __restrict__ ehB,
                                                   const short* __restrict__ elB,
                                                   const float* __restrict__ se,
                                                   float2* __restrict__ mv,
                                                   unsigned long long* __restrict__ kv) {
  #pragma clang fp contract(off)
  __shared__ float sel[256];                     // this quarter's se values
  const int tid  = (int)threadIdx.x;
  const int l    = tid & 63;
  const int wid  = tid >> 6;
  const int quar = (int)blockIdx.x & 3;          // K-quarter: tiles [q*16, q*16+16)
  const int rblk = (int)blockIdx.x >> 2;
  const int t0   = quar * 16;
  sel[tid] = se[t0 * 16 + tid];
  __syncthreads();

  // A-fragments for 2 row-tiles (32 rows/wave)
  const int wrb = rblk * 128 + wid * 32;
  bf16x8 xh[2][2], xl[2][2];
  #pragma unroll
  for (int rt = 0; rt < 2; ++rt) {
    const float* xp = x + (size_t)(wrb + rt * 16 + (l & 15)) * DDIM + (l >> 4) * 8;
    #pragma unroll
    for (int dc = 0; dc < 2; ++dc) {
      const float4 v0 = *reinterpret_cast<const float4*>(xp + dc * 32);
      const float4 v1 = *reinterpret_cast<const float4*>(xp + dc * 32 + 4);
      const float vv[8] = {v0.x, v0.y, v0.z, v0.w, v1.x, v1.y, v1.z, v1.w};
      #pragma unroll
      for (int i = 0; i < 8; ++i) {
        const short h = f2bf(vv[i]);
        xh[rt][dc][i] = h;
        xl[rt][dc][i] = f2bf(vv[i] - bf2f(h));
      }
    }
  }

  float m1v[2][4], m2v[2][4];
  int   m1t[2][4];
  #pragma unroll
  for (int rt = 0; rt < 2; ++rt)
    #pragma unroll
    for (int r = 0; r < 4; ++r) { m1v[rt][r] = INFINITY; m2v[rt][r] = INFINITY; m1t[rt][r] = 0; }

  const size_t lb = (size_t)l * 8;
#define FRAGLD(buf, tt, half2) \
  (*reinterpret_cast<const bf16x8*>((buf) + (size_t)(tt) * 1024 + (half2) * 512 + lb))

  // 2-deep pipeline: tiles t (cur) / t+1 (nxt) in flight while computing.
  bf16x8 c0 = FRAGLD(ehB, t0, 0), c1 = FRAGLD(ehB, t0, 1),
         c2 = FRAGLD(elB, t0, 0), c3 = FRAGLD(elB, t0, 1);
  bf16x8 n0 = FRAGLD(ehB, t0 + 1, 0), n1 = FRAGLD(ehB, t0 + 1, 1),
         n2 = FRAGLD(elB, t0 + 1, 0), n3 = FRAGLD(elB, t0 + 1, 1);

  const f32x4 kz = {0.f, 0.f, 0.f, 0.f};
  #pragma unroll 4
  for (int tt = 0; tt < 16; ++tt) {
    const int t = t0 + tt;
    const int tf = (tt + 2 < 16) ? t + 2 : t0 + 15;   // clamp (dup loads harmless)
    bf16x8 f0 = FRAGLD(ehB, tf, 0), f1 = FRAGLD(ehB, tf, 1),
           f2 = FRAGLD(elB, tf, 0), f3 = FRAGLD(elB, tf, 1);

    f32x4 a0, a1;   // interleave the two row-tiles: dep distance 2 on MFMA pipe
    a0 = mfma16(xh[0][0], c0, kz);  a1 = mfma16(xh[1][0], c0, kz);
    a0 = mfma16(xh[0][1], c1, a0);  a1 = mfma16(xh[1][1], c1, a1);
    a0 = mfma16(xh[0][0], c2, a0);  a1 = mfma16(xh[1][0], c2, a1);
    a0 = mfma16(xh[0][1], c3, a0);  a1 = mfma16(xh[1][1], c3, a1);
    a0 = mfma16(xl[0][0], c0, a0);  a1 = mfma16(xl[1][0], c0, a1);
    a0 = mfma16(xl[0][1], c1, a0);  a1 = mfma16(xl[1][1], c1, a1);

    const float sev = sel[tt * 16 + (l & 15)];
    #pragma unroll
    for (int r = 0; r < 4; ++r) {
      {
        const float d = __builtin_fmaf(-2.0f, a0[r], sev);  // d' = se - 2*dot
        const bool c = d < m1v[0][r];
        m2v[0][r] = fminf(m2v[0][r], fmaxf(m1v[0][r], d));
        m1t[0][r] = c ? t : m1t[0][r];
        m1v[0][r] = fminf(m1v[0][r], d);
      }
      {
        const float d = __builtin_fmaf(-2.0f, a1[r], sev);
        const bool c = d < m1v[1][r];
        m2v[1][r] = fminf(m2v[1][r], fmaxf(m1v[1][r], d));
        m1t[1][r] = c ? t : m1t[1][r];
        m1v[1][r] = fminf(m1v[1][r], d);
      }
    }
    c0 = n0; c1 = n1; c2 = n2; c3 = n3;
    n0 = f0; n1 = f1; n2 = f2; n3 = f3;
  }
#undef FRAGLD

  // 16-lane merge (R6-R18-proven); emit per-quarter partials
  const int colbase = l & 15;
  #pragma unroll
  for (int rt = 0; rt < 2; ++rt) {
    #pragma unroll
    for (int r = 0; r < 4; ++r) {
      float m1 = m1v[rt][r], m2 = m2v[rt][r];
      unsigned long long key =
          ((unsigned long long)fflip(__float_as_uint(m1)) << 32)
          | (unsigned)(m1t[rt][r] * 16 + colbase);
      #pragma unroll
      for (int off = 1; off < 16; off <<= 1) {
        const unsigned long long ok = __shfl_xor(key, off, 16);
        const float om1 = __shfl_xor(m1, off, 16);
        const float om2 = __shfl_xor(m2, off, 16);
        m2 = fminf(fminf(m2, om2), fmaxf(m1, om1));
        m1 = fminf(m1, om1);
        key = (ok < key) ? ok : key;
      }
      if (colbase == 0) {
        const int row = wrb + rt * 16 + (l >> 4) * 4 + r;
        mv[(size_t)quar * NROWS + row] = make_float2(m1, m2);
        kv[(size_t)quar * NROWS + row] = key;
      }
    }
  }
}

// ---------------- combine + certified-row finalize (fused)
__global__ __launch_bounds__(256) void vq_combine_out(const float2* __restrict__ mv,
                                                      const unsigned long long* __restrict__ kv,
                                                      const float* __restrict__ x,
                                                      const float* __restrict__ emb,
                                                      int* __restrict__ list,
                                                      int* __restrict__ cnt,
                                                      float* __restrict__ out,
                                                      double* __restrict__ loss_accum) {
  #pragma clang fp contract(off)
  __shared__ int   sbidx[256];
  __shared__ float wsum[4];
  const int tid = (int)threadIdx.x;
  const int gid = blockIdx.x * 256 + tid;
  const int l   = tid & 63;

  // ---- phase 1: R13 tournament + compaction (verbatim logic)
  {
    const float2 A = mv[gid];
    const float2 B = mv[(size_t)NROWS + gid];
    const float2 C = mv[(size_t)2 * NROWS + gid];
    const float2 D = mv[(size_t)3 * NROWS + gid];
    unsigned long long kg = kv[gid];
    {
      unsigned long long k2 = kv[(size_t)NROWS + gid];     kg = (k2 < kg) ? k2 : kg;
      k2 = kv[(size_t)2 * NROWS + gid];                    kg = (k2 < kg) ? k2 : kg;
      k2 = kv[(size_t)3 * NROWS + gid];                    kg = (k2 < kg) ? k2 : kg;
    }
    const float lo1 = fminf(A.x, B.x), hi1 = fmaxf(A.x, B.x);
    const float lo2 = fminf(C.x, D.x), hi2 = fmaxf(C.x, D.x);
    const float m1g = fminf(lo1, lo2);
    const float sec = fminf(fmaxf(lo1, lo2), fminf(hi1, hi2));  // secondmin{m1}
    const float m2g = fminf(sec, fminf(fminf(A.y, B.y), fminf(C.y, D.y)));
    const bool cert = m2g > m1g + EPSB;
    sbidx[tid] = cert ? (int)(kg & 0xffffffffull) : -1;

    const unsigned long long mask = __ballot(!cert);
    int base = 0;
    if (l == 0 && mask) base = atomicAdd(cnt, (int)__popcll(mask));
    base = __shfl(base, 0, 64);
    if (!cert) {
      const int off = (int)__popcll(mask & ((1ull << l) - 1ull));
      list[base + off] = gid;
    }
  }
  __syncthreads();

  // ---- phase 2: finalize certified rows (proven finalize arithmetic/pattern)
  const int wid = tid >> 6;
  const int sub = l >> 4;    // row within the wave's quad
  const int q16 = l & 15;    // float4 slot within the row
  float lacc = 0.f;

  for (int it = 0; it < 16; ++it) {   // block covers its 256 rows
    const int rloc = it * 16 + wid * 4 + sub;
    const int bi = sbidx[rloc];       // uniform within the 16-lane group
    if (bi < 0) continue;             // ambiguous -> minifinal handles
    const int row = blockIdx.x * 256 + rloc;
    const float4 xv = reinterpret_cast<const float4*>(x)[(size_t)row * 16 + q16];
    const float4 ev = reinterpret_cast<const float4*>(emb)[(size_t)bi * 16 + q16];
    const float da = ev.x - xv.x;
    const float db = ev.y - xv.y;
    const float dc = ev.z - xv.z;
    const float dd = ev.w - xv.w;
    float4 o;
    o.x = xv.x + da; o.y = xv.y + db; o.z = xv.z + dc; o.w = xv.w + dd;
    reinterpret_cast<float4*>(out)[(size_t)row * 16 + q16] = o;
    lacc += da * da + db * db + dc * dc + dd * dd;   // order-insensitive
    if (q16 == 0) out[(size_t)NROWS * DDIM + row] = (float)bi;
  }
  #pragma unroll
  for (int off = 32; off > 0; off >>= 1) lacc += __shfl_down(lacc, off, 64);
  if (l == 0) wsum[wid] = lacc;
  __syncthreads();
  if (tid == 0)
    atomicAdd(loss_accum, (double)(wsum[0] + wsum[1] + wsum[2] + wsum[3]));
}

// ---------------- exact scan (R13-frozen): 1-wave blocks, 32-code LDS parts
__global__ __launch_bounds__(64) void vq_exact(const float* __restrict__ x,
                                               const float* __restrict__ emb,
                                               const float* __restrict__ se,
                                               const int* __restrict__ list,
                                               const int* __restrict__ cnt,
                                               unsigned long long* __restrict__ keyBest) {
  #pragma clang fp contract(off)
  __shared__ __align__(16) float eL[32 * DDIM];   // 8 KB: one part's 32 codes
  const int n = *cnt;
  if (n == 0) return;
  const int nrb = (n + 63) >> 6;
  const int ntasks = nrb * 32;
  const int l = (int)threadIdx.x;                 // 0..63

  for (int t = (int)blockIdx.x; t < ntasks; t += (int)gridDim.x) {
    const int part = t & 31;
    const int rb   = t >> 5;
    const int j0   = part * 32;

    {  // stage this part's 32 e-rows (coalesced float4)
      const float4* src = reinterpret_cast<const float4*>(emb + (size_t)j0 * DDIM);
      float4* dst = reinterpret_cast<float4*>(eL);
      #pragma unroll
      for (int i = 0; i < 8; ++i) dst[i * 64 + l] = src[i * 64 + l];
    }
    __syncthreads();

    const int idx = rb * 64 + l;
    const bool act = idx < n;
    const int row = act ? list[idx] : 0;
    const float4* xr4 = reinterpret_cast<const float4*>(x + (size_t)row * DDIM);

    float xv[DDIM];   // x row -> regs once
    #pragma unroll
    for (int q = 0; q < 16; ++q) {
      const float4 v = xr4[q];
      xv[q * 4 + 0] = v.x; xv[q * 4 + 1] = v.y;
      xv[q * 4 + 2] = v.z; xv[q * 4 + 3] = v.w;
    }

    // sx: numpy pairwise 8-accumulator (R1-proven order)
    float rr[8];
    #pragma unroll
    for (int j = 0; j < 8; ++j) rr[j] = xv[j] * xv[j];
    #pragma unroll
    for (int i = 8; i < DDIM; i += 8) {
      #pragma unroll
      for (int j = 0; j < 8; ++j) rr[j] += xv[i + j] * xv[i + j];
    }
    const float sx = ((rr[0] + rr[1]) + (rr[2] + rr[3])) + ((rr[4] + rr[5]) + (rr[6] + rr[7]));

    unsigned long long best = ~0ull;
    #pragma unroll 1
    for (int g = 0; g < 8; ++g) {   // 8 groups of 4 codes; 4 chains
      const int jb = g * 4;
      const float4* e0 = reinterpret_cast<const float4*>(eL + (jb + 0) * DDIM);
      const float4* e1 = reinterpret_cast<const float4*>(eL + (jb + 1) * DDIM);
      const float4* e2 = reinterpret_cast<const float4*>(eL + (jb + 2) * DDIM);
      const float4* e3 = reinterpret_cast<const float4*>(eL + (jb + 3) * DDIM);
      float a0 = 0.f, a1 = 0.f, a2 = 0.f, a3 = 0.f;
      #pragma unroll
      for (int q = 0; q < 16; ++q) {   // per code: sequential d=0..63 (R1 chain)
        const float4 v0 = e0[q], v1 = e1[q], v2 = e2[q], v3 = e3[q];
        const float xa = xv[q * 4 + 0], xb = xv[q * 4 + 1];
        const float xc = xv[q * 4 + 2], xd = xv[q * 4 + 3];
        a0 = __builtin_fmaf(xa, v0.x, a0); a0 = __builtin_fmaf(xb, v0.y, a0);
        a0 = __builtin_fmaf(xc, v0.z, a0); a0 = __builtin_fmaf(xd, v0.w, a0);
        a1 = __builtin_fmaf(xa, v1.x, a1); a1 = __builtin_fmaf(xb, v1.y, a1);
        a1 = __builtin_fmaf(xc, v1.z, a1); a1 = __builtin_fmaf(xd, v1.w, a1);
        a2 = __builtin_fmaf(xa, v2.x, a2); a2 = __builtin_fmaf(xb, v2.y, a2);
        a2 = __builtin_fmaf(xc, v2.z, a2); a2 = __builtin_fmaf(xd, v2.w, a2);
        a3 = __builtin_fmaf(xa, v3.x, a3); a3 = __builtin_fmaf(xb, v3.y, a3);
        a3 = __builtin_fmaf(xc, v3.z, a3); a3 = __builtin_fmaf(xd, v3.w, a3);
      }
      const int j = j0 + jb;
      const float T0 = sx + se[j + 0];                    // fl(sx + se_j)
      const float T1 = sx + se[j + 1];
      const float T2 = sx + se[j + 2];
      const float T3 = sx + se[j + 3];
      const float di0 = __builtin_fmaf(-2.0f, a0, T0);    // fl(T - 2*acc)
      const float di1 = __builtin_fmaf(-2.0f, a1, T1);
      const float di2 = __builtin_fmaf(-2.0f, a2, T2);
      const float di3 = __builtin_fmaf(-2.0f, a3, T3);
      unsigned long long k;
      k = ((unsigned long long)fflip(__float_as_uint(di0)) << 32) | (unsigned)(j + 0);
      best = (k < best) ? k : best;
      k = ((unsigned long long)fflip(__float_as_uint(di1)) << 32) | (unsigned)(j + 1);
      best = (k < best) ? k : best;
      k = ((unsigned long long)fflip(__float_as_uint(di2)) << 32) | (unsigned)(j + 2);
      best = (k < best) ? k : best;
      k = ((unsigned long long)fflip(__float_as_uint(di3)) << 32) | (unsigned)(j + 3);
      best = (k < best) ? k : best;
    }
    if (act) atomicMin(&keyBest[row], best);   // (dist asc, j asc) == first-min
    __syncthreads();                           // eL reuse barrier (1-wave: cheap)
  }
}

// ---------------- minifinal: ambiguous rows only (keyBest lookup)
__global__ __launch_bounds__(256) void vq_minifinal(const float* __restrict__ x,
                                                    const float* __restrict__ emb,
                                                    const int* __restrict__ list,
                                                    const int* __restrict__ cnt,
                                                    const unsigned long long* __restrict__ keyBest,
                                                    float* __restrict__ out,
                                                    double* __restrict__ loss_accum) {
  #pragma clang fp contract(off)
  const int n = *cnt;
  const int l   = (int)threadIdx.x & 63;
  const int sub = l >> 4;
  const int q16 = l & 15;
  const int w   = blockIdx.x * 4 + ((int)threadIdx.x >> 6);
  const int nW  = (int)gridDim.x * 4;
  float lacc = 0.f;

  for (int base = w * 4; base < n; base += nW * 4) {
    const int i = base + sub;     // uniform within 16-lane group
    if (i >= n) continue;
    const int row = list[i];
    const int bi = (int)(keyBest[row] & 0xffffffffull);
    const float4 xv = reinterpret_cast<const float4*>(x)[(size_t)row * 16 + q16];
    const float4 ev = reinterpret_cast<const float4*>(emb)[(size_t)bi * 16 + q16];
    const float da = ev.x - xv.x;
    const float db = ev.y - xv.y;
    const float dc = ev.z - xv.z;
    const float dd = ev.w - xv.w;
    float4 o;
    o.x = xv.x + da; o.y = xv.y + db; o.z = xv.z + dc; o.w = xv.w + dd;
    reinterpret_cast<float4*>(out)[(size_t)row * 16 + q16] = o;
    lacc += da * da + db * db + dc * dc + dd * dd;
    if (q16 == 0) out[(size_t)NROWS * DDIM + row] = (float)bi;
  }
  #pragma unroll
  for (int off = 32; off > 0; off >>= 1) lacc += __shfl_down(lacc, off, 64);
  if (l == 0 && lacc != 0.f) atomicAdd(loss_accum, (double)lacc);
}

// ---------------- scalars
__global__ void vq_scalars(const double* __restrict__ loss_accum,
                           float* __restrict__ out) {
  if (threadIdx.x == 0 && blockIdx.x == 0) {
    const double mm = *loss_accum / (double)((size_t)NROWS * DDIM);
    const float el = (float)mm;
    float* tail = out + (size_t)NROWS * DDIM + NROWS;
    tail[0] = 0.25f * el;
    tail[1] = el;
    tail[2] = 0.0f;
  }
}

// ============================================================================
extern "C" void kernel_launch(void* const* d_in, const int* in_sizes, int n_in,
                              void* d_out, int out_size, void* d_ws, size_t ws_size,
                              hipStream_t stream) {
  const float* x   = (const float*)d_in[0];  // [N, 64]
  const float* emb = (const float*)d_in[1];  // [K, 64]
  float* out = (float*)d_out;
  char* ws = (char*)d_ws;

  double* loss_accum = (double*)(ws + WS_LOSS);
  int*    cnt        = (int*)(ws + WS_CNT);
  float*  se         = (float*)(ws + WS_SE);
  short*  ehB        = (short*)(ws + WS_EHB);
  short*  elB        = (short*)(ws + WS_ELB);
  int*    list       = (int*)(ws + WS_LIST);
  unsigned long long* keyBest = (unsigned long long*)(ws + WS_KEY);
  float2* mv         = (float2*)(ws + WS_MV);
  unsigned long long* kv = (unsigned long long*)(ws + WS_KV);

  vq_prep<<<NROWS / 256, 256, 0, stream>>>(emb, se, ehB, elB, keyBest,
                                           loss_accum, cnt);
  vq_fused<<<(NROWS / 128) * 4, 256, 0, stream>>>(x, ehB, elB, se, mv, kv);
  vq_combine_out<<<NROWS / 256, 256, 0, stream>>>(mv, kv, x, emb, list, cnt,
                                                  out, loss_accum);
  vq_exact<<<2048, 64, 0, stream>>>(x, emb, se, list, cnt, keyBest);
  vq_minifinal<<<256, 256, 0, stream>>>(x, emb, list, cnt, keyBest, out,
                                        loss_accum);
  vq_scalars<<<1, 64, 0, stream>>>(loss_accum, out);
}